// Round 5
// baseline (468.282 us; speedup 1.0000x reference)
//
#include <hip/hip_runtime.h>

#define Tq   4096
#define HIDN 2048
#define NHEAD 16
#define NKV  8
#define DH   128
#define QKVN 4096   // qkv rows-out width (Q 2048 | K 1024 | V 1024)

typedef unsigned short u16;
typedef unsigned int   u32;
typedef __attribute__((ext_vector_type(8))) __bf16 bf16x8;
typedef __attribute__((ext_vector_type(8))) u16    u16x8;
typedef __attribute__((ext_vector_type(4))) float  f32x4;

// global->LDS direct copy, 16B per lane, LDS dest = wave-uniform base + lane*16
#define GLD16(gp, lp) __builtin_amdgcn_global_load_lds( \
    (const __attribute__((address_space(1))) void*)(gp), \
    (__attribute__((address_space(3))) void*)(lp), 16, 0, 0)

__device__ __forceinline__ u16 f2bf(float f) {   // RNE fp32->bf16
  union { float f; u32 u; } v; v.f = f;
  return (u16)((v.u + 0x7fffu + ((v.u >> 16) & 1u)) >> 16);
}
__device__ __forceinline__ float bf2f(u32 bits) {
  union { u32 u; float f; } v; v.u = bits << 16;
  return v.f;
}

// ---------------- cast fp32 -> bf16, n multiple of 2048 ----------------
__global__ __launch_bounds__(256) void cast_bf16_kernel(const float* __restrict__ in,
                                                        u16* __restrict__ out, int n) {
  int i = (blockIdx.x * 256 + threadIdx.x) * 8;
  if (i >= n) return;
  f32x4 a = *(const f32x4*)(in + i);
  f32x4 b = *(const f32x4*)(in + i + 4);
  u16x8 o;
  #pragma unroll
  for (int j = 0; j < 4; ++j) { o[j] = f2bf(a[j]); o[4 + j] = f2bf(b[j]); }
  *(u16x8*)(out + i) = o;
}

// ---------------- GEMM: C[m][n] = sum_k A[m][k]*B[n][k], bf16 in ----------------
template<bool OUT_BF16>
__global__ __launch_bounds__(256) void gemm_bt_kernel(const u16* __restrict__ A,
                                                      const u16* __restrict__ B,
                                                      void* __restrict__ Cout,
                                                      int M, int N, int K) {
  __shared__ u16 As[128 * 32];
  __shared__ u16 Bs[128 * 32];
  const int tid = threadIdx.x;
  const int lane = tid & 63, wv = tid >> 6;
  const int wr = wv >> 1, wc = wv & 1;
  const int g = lane >> 4, c = lane & 15;
  const int nbn = N >> 7;
  const int bm = blockIdx.x / nbn, bn = blockIdx.x % nbn;
  const int m0 = bm << 7, n0 = bn << 7;

  const int srow = tid >> 2;
  const int sk8 = (tid & 3) * 8;
  const u16* gA0 = A + (size_t)(m0 + srow) * K + sk8;
  const u16* gA1 = gA0 + (size_t)64 * K;
  const u16* gB0 = B + (size_t)(n0 + srow) * K + sk8;
  const u16* gB1 = gB0 + (size_t)64 * K;
  u16* lA0 = As + (wv * 64) * 8;
  u16* lA1 = As + (wv * 64 + 256) * 8;
  u16* lB0 = Bs + (wv * 64) * 8;
  u16* lB1 = Bs + (wv * 64 + 256) * 8;

  f32x4 acc[4][4] = {};

  for (int kt = 0; kt < K; kt += 32) {
    __syncthreads();
    GLD16(gA0 + kt, lA0); GLD16(gA1 + kt, lA1);
    GLD16(gB0 + kt, lB0); GLD16(gB1 + kt, lB1);
    __syncthreads();
    bf16x8 af[4], bfr[4];
    #pragma unroll
    for (int mi = 0; mi < 4; ++mi)
      af[mi] = *(const bf16x8*)&As[(wr * 64 + mi * 16 + c) * 32 + g * 8];
    #pragma unroll
    for (int ni = 0; ni < 4; ++ni)
      bfr[ni] = *(const bf16x8*)&Bs[(wc * 64 + ni * 16 + c) * 32 + g * 8];
    #pragma unroll
    for (int mi = 0; mi < 4; ++mi)
      #pragma unroll
      for (int ni = 0; ni < 4; ++ni)
        acc[mi][ni] = __builtin_amdgcn_mfma_f32_16x16x32_bf16(af[mi], bfr[ni], acc[mi][ni], 0, 0, 0);
  }

  #pragma unroll
  for (int mi = 0; mi < 4; ++mi)
    #pragma unroll
    for (int ni = 0; ni < 4; ++ni) {
      const int row = m0 + wr * 64 + mi * 16 + 4 * g;
      const int col = n0 + wc * 64 + ni * 16 + c;
      #pragma unroll
      for (int j = 0; j < 4; ++j) {
        if (OUT_BF16) ((u16*)Cout)[(size_t)(row + j) * N + col] = f2bf(acc[mi][ni][j]);
        else          ((float*)Cout)[(size_t)(row + j) * N + col] = acc[mi][ni][j];
      }
    }
}

// ---------------- fused RMSNorm + RoPE, in place on q|k of qkv ----------------
__global__ __launch_bounds__(256) void normrope_kernel(u16* __restrict__ qkv,
                                                       const float* __restrict__ qw,
                                                       const float* __restrict__ kw) {
  const int tid = threadIdx.x, lane = tid & 63, wv = tid >> 6;
  const int wid = blockIdx.x * 4 + wv;
  const int t = wid / 24;
  const int hh = wid % 24;
  const int off = (hh < 16) ? hh * DH : 2048 + (hh - 16) * DH;
  const float* w = (hh < 16) ? qw : kw;
  u16* base = qkv + (size_t)t * QKVN + off;
  const int d0 = lane * 2;

  u32 raw = *(const u32*)(base + d0);
  float v0 = bf2f(raw & 0xffffu), v1 = bf2f(raw >> 16);
  float ss = v0 * v0 + v1 * v1;
  #pragma unroll
  for (int m = 1; m <= 32; m <<= 1) ss += __shfl_xor(ss, m);
  const float rn = rsqrtf(ss * (1.0f / 128.0f) + 1e-6f);
  float n0 = v0 * rn * w[d0];
  float n1 = v1 * rn * w[d0 + 1];
  float o0 = __shfl_xor(n0, 32);
  float o1 = __shfl_xor(n1, 32);
  const int j0 = (lane & 31) * 2;
  const float p = (float)t;                // positions == arange(T) by construction
  const float lf = 0.31143075889568947f;   // log2(1e6)/64
  float a0 = p * __builtin_exp2f(-lf * (float)j0);
  float a1 = p * __builtin_exp2f(-lf * (float)(j0 + 1));
  float c0 = cosf(a0), s0 = sinf(a0), c1 = cosf(a1), s1 = sinf(a1);
  float r0, r1;
  if (lane < 32) { r0 = n0 * c0 - o0 * s0; r1 = n1 * c1 - o1 * s1; }
  else           { r0 = n0 * c0 + o0 * s0; r1 = n1 * c1 + o1 * s1; }
  *(u32*)(base + d0) = (u32)f2bf(r0) | ((u32)f2bf(r1) << 16);
}

// ---------------- V transpose: qkv v-section [t][kvh][d] -> vt[kvh][d][t] ----------------
__global__ __launch_bounds__(256) void vtrans_kernel(const u16* __restrict__ qkv,
                                                     u16* __restrict__ vt) {
  __shared__ u16 tile[64][72];
  const int tid = threadIdx.x;
  const int b = blockIdx.x;
  const int kvh = b >> 7;
  const int r = b & 127;
  const int t0 = (r & 63) * 64;
  const int d0 = (r >> 6) * 64;
  #pragma unroll
  for (int i = 0; i < 2; ++i) {
    int cidx = tid + i * 256;
    int trow = cidx >> 3, dcol = (cidx & 7) * 8;
    u16x8 v = *(const u16x8*)&qkv[(size_t)(t0 + trow) * QKVN + 3072 + kvh * DH + d0 + dcol];
    *(u16x8*)&tile[trow][dcol] = v;
  }
  __syncthreads();
  #pragma unroll
  for (int i = 0; i < 2; ++i) {
    int cidx = tid + i * 256;
    int drow = cidx >> 3, tcol = (cidx & 7) * 8;
    u16x8 v;
    #pragma unroll
    for (int j = 0; j < 8; ++j) v[j] = tile[tcol + j][drow];
    *(u16x8*)&vt[(size_t)kvh * DH * Tq + (size_t)(d0 + drow) * Tq + t0 + tcol] = v;
  }
}

// ---------------- flash attention, causal, GQA — 2 blocks/CU overlap ----------------
// Grid 512 x 256 threads (4 waves): block = (head, pair p) handles 64-row q-tiles
// {p, 63-p} => uniform 65 phases. 2 independent barrier domains per CU so one
// block's staging stall overlaps the other's MFMA (m114 wave-level overlap).
// Reg-prefetch staging (T14); ones-row row-sums; defer-max (T13); cvt_pk packing.
__global__ __launch_bounds__(256) void attn4_kernel(const u16* __restrict__ qkv,
                                                    const u16* __restrict__ vt,
                                                    u16* __restrict__ o) {
  __shared__ u16 Ks[64 * 128];             // 16 KB, dest-swizzled
  __shared__ u16 Vs[144 * 64];             // 18 KB: rows 0..127 V^T, 128=ones, 129..143=0
  __shared__ u16 Ps[4][16][72];            // per-wave P staging
  const int tid = threadIdx.x, lane = tid & 63, wv = tid >> 6;
  const int g = lane >> 4, c = lane & 15;
  const int bid = blockIdx.x;
  const int head = bid & 15;
  const int p = bid >> 4;                  // 0..31
  const int kvh = head >> 1;
  const float c2 = 0.08838834764831845f * 1.4426950408889634f;  // scale*log2(e)
  const float THR = 40.0f;                 // defer-max threshold (raw score units)
  const int xk = c & 7;                    // read-side swizzle key

  // ones/zero rows of Vs (rows 128..143), written once; row-constant => swizzle-proof
  for (int i = tid; i < 16 * 64; i += 256) Vs[128 * 64 + i] = (i < 64) ? 0x3F80 : 0;

  // staging geometry: thread handles chunks i = j*256+tid, j=0..3 for K and V
  int kOff[4], kDst[4], vOff[4], vDst[4];
  #pragma unroll
  for (int j = 0; j < 4; ++j) {
    int i = j * 256 + tid;
    int kr = i >> 4, kcc = i & 15;         // K: 64 rows x 16 chunks
    kOff[j] = kr * QKVN + 2048 + kvh * DH + kcc * 8;
    kDst[j] = kr * 128 + ((kcc ^ (kr & 7)) * 8);
    int vr = i >> 3, vcc = i & 7;          // V: 128 rows x 8 chunks
    vOff[j] = vr * Tq + vcc * 8;
    vDst[j] = vr * 64 + ((vcc ^ (vr & 7)) * 8);
  }
  const u16* vkv = vt + (size_t)kvh * DH * Tq;
  u16x8 kreg[4], vreg[4];

  #pragma unroll 1
  for (int seg = 0; seg < 2; ++seg) {
    const int qt = seg ? (63 - p) : p;     // 64-row q-tile index
    const int q0w = qt * 64 + wv * 16;
    const int nkvb = qt + 1;

    bf16x8 qf[4];
    #pragma unroll
    for (int ks = 0; ks < 4; ++ks)
      qf[ks] = *(const bf16x8*)&qkv[(size_t)(q0w + c) * QKVN + head * DH + ks * 32 + g * 8];

    f32x4 oacc[9] = {};                    // [0..7]=O cols, [8]=row-sum (ones col)
    float mrow[4] = { -3e38f, -3e38f, -3e38f, -3e38f };

    // prologue prefetch of tile 0
    #pragma unroll
    for (int j = 0; j < 4; ++j) {
      kreg[j] = *(const u16x8*)(qkv + kOff[j]);
      vreg[j] = *(const u16x8*)(vkv + vOff[j]);
    }

    for (int kb = 0; kb < nkvb; ++kb) {
      const int kv0 = kb * 64;
      // commit prefetched regs to LDS
      #pragma unroll
      for (int j = 0; j < 4; ++j) {
        *(u16x8*)&Ks[kDst[j]] = kreg[j];
        *(u16x8*)&Vs[vDst[j]] = vreg[j];
      }
      __syncthreads();                     // tiles visible
      {                                    // prefetch next tile (clamped) into regs
        const int kvn = (kb + 1 < nkvb) ? (kv0 + 64) : kv0;
        #pragma unroll
        for (int j = 0; j < 4; ++j) {
          kreg[j] = *(const u16x8*)(qkv + (size_t)kvn * QKVN + kOff[j]);
          vreg[j] = *(const u16x8*)(vkv + kvn + vOff[j]);
        }
      }
      if (kv0 <= q0w + 15) {               // wave-uniform active gate
        f32x4 s[4] = {};
        #pragma unroll
        for (int st = 0; st < 4; ++st)
          #pragma unroll
          for (int ks = 0; ks < 4; ++ks) {
            bf16x8 kf = *(const bf16x8*)&Ks[(st * 16 + c) * 128 + (((ks * 4 + g) ^ xk) * 8)];
            s[st] = __builtin_amdgcn_mfma_f32_16x16x32_bf16(qf[ks], kf, s[st], 0, 0, 0);
          }
        if (kv0 + 63 > q0w) {              // diagonal: causal mask
          #pragma unroll
          for (int st = 0; st < 4; ++st) {
            const int kvc = kv0 + st * 16 + c;
            #pragma unroll
            for (int j = 0; j < 4; ++j)
              if (kvc > q0w + 4 * g + j) s[st][j] = -1e9f;
          }
        }
        // row max + defer-max check
        float mx[4];
        int need = 0;
        #pragma unroll
        for (int j = 0; j < 4; ++j) {
          float m3 = fmaxf(fmaxf(s[0][j], s[1][j]), fmaxf(s[2][j], s[3][j]));
          m3 = fmaxf(m3, __shfl_xor(m3, 1));
          m3 = fmaxf(m3, __shfl_xor(m3, 2));
          m3 = fmaxf(m3, __shfl_xor(m3, 4));
          m3 = fmaxf(m3, __shfl_xor(m3, 8));
          mx[j] = m3;
          need |= (m3 > mrow[j] + THR);
        }
        if (__any(need)) {                 // rescale path (rare after warmup)
          #pragma unroll
          for (int j = 0; j < 4; ++j) {
            const float mn = fmaxf(mrow[j], mx[j]);
            const float alpha = __builtin_exp2f(c2 * (mrow[j] - mn));
            mrow[j] = mn;
            #pragma unroll
            for (int db = 0; db < 9; ++db) oacc[db][j] *= alpha;
          }
        }
        // exponentials (stale-max safe: bounded by exp2(c2*THR)~=34)
        #pragma unroll
        for (int j = 0; j < 4; ++j) {
          const float cm = c2 * mrow[j];
          #pragma unroll
          for (int st = 0; st < 4; ++st)
            s[st][j] = __builtin_exp2f(c2 * s[st][j] - cm);
        }
        // pack P -> bf16 pairs, stage to LDS (C layout rows 4g+j)
        #pragma unroll
        for (int st = 0; st < 4; ++st) {
          u32 pk01, pk23;
          asm("v_cvt_pk_bf16_f32 %0, %1, %2" : "=v"(pk01) : "v"(s[st][0]), "v"(s[st][1]));
          asm("v_cvt_pk_bf16_f32 %0, %1, %2" : "=v"(pk23) : "v"(s[st][2]), "v"(s[st][3]));
          Ps[wv][4 * g + 0][st * 16 + c] = (u16)pk01;
          Ps[wv][4 * g + 1][st * 16 + c] = (u16)(pk01 >> 16);
          Ps[wv][4 * g + 2][st * 16 + c] = (u16)pk23;
          Ps[wv][4 * g + 3][st * 16 + c] = (u16)(pk23 >> 16);
        }
        bf16x8 pa0 = *(const bf16x8*)&Ps[wv][c][g * 8];
        bf16x8 pa1 = *(const bf16x8*)&Ps[wv][c][32 + g * 8];
        #pragma unroll
        for (int db = 0; db < 9; ++db) {
          bf16x8 vf0 = *(const bf16x8*)&Vs[(db * 16 + c) * 64 + ((g ^ xk) * 8)];
          oacc[db] = __builtin_amdgcn_mfma_f32_16x16x32_bf16(pa0, vf0, oacc[db], 0, 0, 0);
          bf16x8 vf1 = *(const bf16x8*)&Vs[(db * 16 + c) * 64 + (((4 + g) ^ xk) * 8)];
          oacc[db] = __builtin_amdgcn_mfma_f32_16x16x32_bf16(pa1, vf1, oacc[db], 0, 0, 0);
        }
      }
      __syncthreads();                     // all reads done before next phase's writes
    }

    // epilogue: lsum lives on c==0 lanes of oacc[8]; broadcast within 16-lane group
    #pragma unroll
    for (int j = 0; j < 4; ++j) {
      const float ls = __shfl(oacc[8][j], lane & 48);
      const float inv = 1.0f / ls;
      #pragma unroll
      for (int db = 0; db < 8; ++db)
        o[(size_t)(q0w + 4 * g + j) * HIDN + head * DH + db * 16 + c] = f2bf(oacc[db][j] * inv);
    }
  }
}

// ---------------- launch ----------------
extern "C" void kernel_launch(void* const* d_in, const int* in_sizes, int n_in,
                              void* d_out, int out_size, void* d_ws, size_t ws_size,
                              hipStream_t stream) {
  const float* x    = (const float*)d_in[0];
  const float* qkvw = (const float*)d_in[1];
  const float* qnw  = (const float*)d_in[2];
  const float* knw  = (const float*)d_in[3];
  const float* ow   = (const float*)d_in[4];

  char* ws = (char*)d_ws;
  u16* xb   = (u16*)ws;                      // 16 MB, reused for ow_bf16 after GEMM1
  u16* wb   = (u16*)(ws + (16u << 20));      // 16 MB, reused for attn-out after GEMM1
  u16* qkvb = (u16*)(ws + (32u << 20));      // 32 MB
  u16* vtb  = (u16*)(ws + (64u << 20));      // 8 MB   (total 72 MB)
  u16* owb  = xb;
  u16* ob   = wb;

  cast_bf16_kernel<<<4096, 256, 0, stream>>>(x,    xb, Tq * HIDN);
  cast_bf16_kernel<<<4096, 256, 0, stream>>>(qkvw, wb, QKVN * HIDN);
  gemm_bt_kernel<true><<<1024, 256, 0, stream>>>(xb, wb, (void*)qkvb, Tq, QKVN, HIDN);
  normrope_kernel<<<24576, 256, 0, stream>>>(qkvb, qnw, knw);
  vtrans_kernel<<<1024, 256, 0, stream>>>(qkvb, vtb);
  cast_bf16_kernel<<<2048, 256, 0, stream>>>(ow, owb, HIDN * HIDN);
  attn4_kernel<<<512, 256, 0, stream>>>(qkvb, vtb, ob);
  gemm_bt_kernel<false><<<512, 256, 0, stream>>>(ob, owb, d_out, Tq, HIDN, HIDN);
}